// Round 7
// baseline (220.421 us; speedup 1.0000x reference)
//
#include <hip/hip_runtime.h>
#include <hip/hip_fp16.h>

#define N_NODES 50000
#define N_EDGES 800000
#define IN_DIM  128
#define OUT_DIM 256
#define SCAN_BLOCKS ((N_NODES + 255) / 256)  // 196
#define WT_STRIDE 136  // f16 elems; 272B rows -> 2-way-max bank spread (free)

typedef _Float16 f16x8 __attribute__((ext_vector_type(8)));
typedef float f32x4 __attribute__((ext_vector_type(4)));

// ---------------------------------------------------------------------------
// Uniform int64-vs-int32 detection (values < 2^31 -> int64 odd words all 0).
// ---------------------------------------------------------------------------
__device__ __forceinline__ int detect_i64(const int* __restrict__ idx) {
  int orv = 0;
#pragma unroll
  for (int j = 1; j < 32; j += 2) orv |= idx[j];
  return orv == 0;
}

// ---------------------------------------------------------------------------
// Kernel 1: dst histogram + per-edge slot + f32->f16 feat cast (fused).
// Grid 3125x256 covers N_EDGES exactly; cast covers 6.4M floats exactly.
// ---------------------------------------------------------------------------
__global__ __launch_bounds__(256) void hist_cast(
    const int* __restrict__ dst, const float* __restrict__ feat,
    __half* __restrict__ feat16, int* __restrict__ hist,
    int* __restrict__ slot) {
  const int f = detect_i64(dst);
  const int e = blockIdx.x * 256 + threadIdx.x;
  const int d = dst[f ? 2 * (long)e : (long)e];
  slot[e] = atomicAdd(&hist[d], 1);

  if (feat16 != nullptr) {
    size_t i = (size_t)e * 8;
    float4 v0 = *reinterpret_cast<const float4*>(feat + i);
    float4 v1 = *reinterpret_cast<const float4*>(feat + i + 4);
    __half2 h[4];
    h[0] = __floats2half2_rn(v0.x, v0.y);
    h[1] = __floats2half2_rn(v0.z, v0.w);
    h[2] = __floats2half2_rn(v1.x, v1.y);
    h[3] = __floats2half2_rn(v1.z, v1.w);
    *reinterpret_cast<float4*>(feat16 + i) = *reinterpret_cast<float4*>(h);
  }
}

// ---------------------------------------------------------------------------
// Kernel 2: per-block exclusive scan of hist into row_start + bsum.
// Blocks 0..127 additionally transpose+cast W into global WT16g[n][k]
// (uniform-per-block branch; 128KB table, runs in parallel with the scan).
// ---------------------------------------------------------------------------
__global__ __launch_bounds__(256) void scan_block(
    const int* __restrict__ hist, int* __restrict__ row_start,
    int* __restrict__ bsum, const float* __restrict__ W,
    __half* __restrict__ WT16g) {
  __shared__ int s[256];
  int tid = threadIdx.x;
  int i = blockIdx.x * 256 + tid;
  int v = (i < N_NODES) ? hist[i] : 0;
  s[tid] = v;
  __syncthreads();
  for (int off = 1; off < 256; off <<= 1) {
    int t = (tid >= off) ? s[tid - off] : 0;
    __syncthreads();
    s[tid] += t;
    __syncthreads();
  }
  if (i < N_NODES) row_start[i] = s[tid] - v;
  if (tid == 255) bsum[blockIdx.x] = s[255];

  if (blockIdx.x < 128) {  // W transpose: block b -> n rows 2b, 2b+1
    int n = 2 * blockIdx.x + (tid >> 7);
    int k = tid & 127;
    WT16g[n * IN_DIM + k] = __float2half(W[k * OUT_DIM + n]);
  }
}

// ---------------------------------------------------------------------------
// Kernel 3: add block prefix (redundant per-block reduce of bsum).
// ---------------------------------------------------------------------------
__global__ __launch_bounds__(256) void scan_add(
    const int* __restrict__ bsum, int* __restrict__ row_start) {
  __shared__ int sb[256];
  int tid = threadIdx.x;
  sb[tid] = (tid < (int)blockIdx.x) ? bsum[tid] : 0;
  __syncthreads();
  for (int off = 128; off > 0; off >>= 1) {
    if (tid < off) sb[tid] += sb[tid + off];
    __syncthreads();
  }
  int i = blockIdx.x * 256 + tid;
  if (i < N_NODES) row_start[i] += sb[0];
  if (i == 0) row_start[N_NODES] = N_EDGES;
}

// ---------------------------------------------------------------------------
// Kernel 4: scatter src into dst-sorted esrc, 2 edges/thread, vector loads.
// int64 path: int4 load = {lo0,hi0,lo1,hi1} -> lows at .x,.z.
// ---------------------------------------------------------------------------
__global__ __launch_bounds__(256) void scatter_kernel(
    const int* __restrict__ src, const int* __restrict__ dst,
    const int* __restrict__ row_start, const int* __restrict__ slot,
    int* __restrict__ esrc) {
  const int f = detect_i64(src);
  const int t = blockIdx.x * 256 + threadIdx.x;
  if (t >= N_EDGES / 2) return;
  int s0, s1, d0, d1;
  if (f) {
    int4 sv = *reinterpret_cast<const int4*>(src + 4 * (long)t);
    int4 dv = *reinterpret_cast<const int4*>(dst + 4 * (long)t);
    s0 = sv.x; s1 = sv.z; d0 = dv.x; d1 = dv.z;
  } else {
    int2 sv = *reinterpret_cast<const int2*>(src + 2 * (long)t);
    int2 dv = *reinterpret_cast<const int2*>(dst + 2 * (long)t);
    s0 = sv.x; s1 = sv.y; d0 = dv.x; d1 = dv.y;
  }
  int2 sl = *reinterpret_cast<const int2*>(slot + 2 * (long)t);
  esrc[row_start[d0] + sl.x] = s0;
  esrc[row_start[d1] + sl.y] = s1;
}

// ---------------------------------------------------------------------------
// Kernel 5: pull aggregation, one wave per node, masked unroll-8
// (8 independent gathers in flight; tail handled by index clamp + cndmask).
// ---------------------------------------------------------------------------
__global__ __launch_bounds__(256) void aggregate_f16(
    const float* __restrict__ feat, const __half* __restrict__ feat16,
    const int* __restrict__ esrc, const int* __restrict__ row_start,
    __half2* __restrict__ x) {
  int node = blockIdx.x * 4 + ((int)threadIdx.x >> 6);
  int lane = (int)threadIdx.x & 63;
  if (node >= N_NODES) return;
  int rs = row_start[node];
  int re = row_start[node + 1];

  float2 a[8];
#pragma unroll
  for (int j = 0; j < 8; ++j) a[j] = {0.f, 0.f};

  for (int e = rs; e < re; e += 8) {
    int idx[8];
#pragma unroll
    for (int j = 0; j < 8; ++j) idx[j] = esrc[min(e + j, re - 1)];
#pragma unroll
    for (int j = 0; j < 8; ++j) {
      float2 v = __half22float2(*reinterpret_cast<const __half2*>(
          feat16 + (size_t)idx[j] * IN_DIM + lane * 2));
      if (e + j < re) {
        a[j].x += v.x;
        a[j].y += v.y;
      }
    }
  }
  float sx = ((a[0].x + a[1].x) + (a[2].x + a[3].x)) +
             ((a[4].x + a[5].x) + (a[6].x + a[7].x));
  float sy = ((a[0].y + a[1].y) + (a[2].y + a[3].y)) +
             ((a[4].y + a[5].y) + (a[6].y + a[7].y));
  float deg = (float)(re - rs);
  float rdeg = (deg > 0.f) ? 1.0f / deg : 0.0f;
  float2 f = *reinterpret_cast<const float2*>(
      feat + (size_t)node * IN_DIM + lane * 2);
  float x0 = (f.x + sx * rdeg) * 0.5f;
  float x1 = (f.y + sy * rdeg) * 0.5f;
  x[(size_t)node * (IN_DIM / 2) + lane] = __floats2half2_rn(x0, x1);
}

// f32-gather fallback (only if workspace can't hold feat16).
__global__ __launch_bounds__(256) void aggregate_f32(
    const float* __restrict__ feat, const int* __restrict__ esrc,
    const int* __restrict__ row_start, __half2* __restrict__ x) {
  int node = blockIdx.x * 4 + ((int)threadIdx.x >> 6);
  int lane = (int)threadIdx.x & 63;
  if (node >= N_NODES) return;
  int rs = row_start[node];
  int re = row_start[node + 1];
  float2 a0 = {0.f, 0.f}, a1 = {0.f, 0.f};
  int e = rs;
  for (; e + 1 < re; e += 2) {
    float2 v0 = *reinterpret_cast<const float2*>(
        feat + (size_t)esrc[e] * IN_DIM + lane * 2);
    float2 v1 = *reinterpret_cast<const float2*>(
        feat + (size_t)esrc[e + 1] * IN_DIM + lane * 2);
    a0.x += v0.x; a0.y += v0.y;
    a1.x += v1.x; a1.y += v1.y;
  }
  if (e < re) {
    float2 v0 = *reinterpret_cast<const float2*>(
        feat + (size_t)esrc[e] * IN_DIM + lane * 2);
    a0.x += v0.x; a0.y += v0.y;
  }
  float deg = (float)(re - rs);
  float rdeg = (deg > 0.f) ? 1.0f / deg : 0.0f;
  float2 f = *reinterpret_cast<const float2*>(
      feat + (size_t)node * IN_DIM + lane * 2);
  float x0 = (f.x + (a0.x + a1.x) * rdeg) * 0.5f;
  float x1 = (f.y + (a0.y + a1.y) * rdeg) * 0.5f;
  x[(size_t)node * (IN_DIM / 2) + lane] = __floats2half2_rn(x0, x1);
}

// ---------------------------------------------------------------------------
// Kernel 6: MFMA GEMM out = relu(x @ W). 512 threads / 8 waves / 256 rows.
// WT staged from pre-transposed global WT16g via pure b128 copy.
// C/D layout (m89-verified): col=lane&15, row=(lane>>4)*4+reg.
// ---------------------------------------------------------------------------
__global__ __launch_bounds__(512) void mfma_gemm(
    const _Float16* __restrict__ x, const __half* __restrict__ WT16g,
    float* __restrict__ out) {
  __shared__ _Float16 WT[OUT_DIM * WT_STRIDE];  // 68 KiB -> 2 blocks/CU

  const int tid = threadIdx.x;
  // Stage: 64 KB = 4096 16B-chunks; thread t copies chunks t, t+512, ... (x8).
#pragma unroll
  for (int i = 0; i < 8; ++i) {
    int c = i * 512 + tid;          // 16B-chunk index
    int n = c >> 4;                 // 16 chunks per n-row (128 f16)
    int kc = c & 15;
    *reinterpret_cast<float4*>(&WT[n * WT_STRIDE + kc * 8]) =
        *reinterpret_cast<const float4*>(WT16g + c * 8);
  }
  __syncthreads();

  const int wave = tid >> 6;
  const int lane = tid & 63;
  const int m = lane & 15;
  const int g = lane >> 4;
  const long row_base = (long)blockIdx.x * 256 + wave * 32;

  f16x8 a[2][4];
#pragma unroll
  for (int rt = 0; rt < 2; ++rt) {
    long row = row_base + rt * 16 + m;
#pragma unroll
    for (int kt = 0; kt < 4; ++kt) {
      if (row < N_NODES) {
        a[rt][kt] = *reinterpret_cast<const f16x8*>(
            x + row * IN_DIM + kt * 32 + g * 8);
      } else {
        a[rt][kt] = f16x8{};
      }
    }
  }

#pragma unroll
  for (int nt = 0; nt < 16; ++nt) {
    f16x8 b[4];
#pragma unroll
    for (int kt = 0; kt < 4; ++kt) {
      b[kt] = *reinterpret_cast<const f16x8*>(
          &WT[(nt * 16 + m) * WT_STRIDE + kt * 32 + g * 8]);
    }
    f32x4 acc0 = {0.f, 0.f, 0.f, 0.f};
    f32x4 acc1 = {0.f, 0.f, 0.f, 0.f};
#pragma unroll
    for (int kt = 0; kt < 4; ++kt) {
      acc0 = __builtin_amdgcn_mfma_f32_16x16x32_f16(a[0][kt], b[kt], acc0, 0, 0, 0);
      acc1 = __builtin_amdgcn_mfma_f32_16x16x32_f16(a[1][kt], b[kt], acc1, 0, 0, 0);
    }
    const int col = nt * 16 + m;
#pragma unroll
    for (int j = 0; j < 4; ++j) {
      long r0 = row_base + g * 4 + j;
      long r1 = row_base + 16 + g * 4 + j;
      if (r0 < N_NODES)
        __builtin_nontemporal_store(fmaxf(acc0[j], 0.f),
                                    &out[r0 * OUT_DIM + col]);
      if (r1 < N_NODES)
        __builtin_nontemporal_store(fmaxf(acc1[j], 0.f),
                                    &out[r1 * OUT_DIM + col]);
    }
  }
}

extern "C" void kernel_launch(void* const* d_in, const int* in_sizes, int n_in,
                              void* d_out, int out_size, void* d_ws,
                              size_t ws_size, hipStream_t stream) {
  const float* feat = (const float*)d_in[0];
  const float* W = (const float*)d_in[1];
  const int* src = (const int*)d_in[2];
  const int* dst = (const int*)d_in[3];
  float* out = (float*)d_out;

  // Workspace (~29.3 MB; ws >= 29.23 MB proven by round-5/6 f16-path runs).
  // slot aliases x: slot dies (scatter) before x is born (aggregate).
  char* p = (char*)d_ws;
  __half* x = (__half*)p;    p += (size_t)N_NODES * IN_DIM * 2;  // 12.8 MB
  int* slot = (int*)x;                                           // 3.2 MB alias
  int* esrc = (int*)p;       p += (size_t)N_EDGES * 4;           // 3.2 MB
  int* hist = (int*)p;       p += (size_t)N_NODES * 4;           // 200 KB
  int* row_start = (int*)p;  p += (size_t)(N_NODES + 1) * 4;
  int* bsum = (int*)p;       p += 256 * 4;
  p = (char*)(((uintptr_t)p + 15) & ~(uintptr_t)15);
  __half* WT16g = (__half*)p; p += (size_t)OUT_DIM * IN_DIM * 2;  // 64 KB
  __half* feat16 = (__half*)p;
  size_t need_f16 =
      ((char*)feat16 - (char*)d_ws) + (size_t)N_NODES * IN_DIM * 2;
  const bool f16_path = (ws_size >= need_f16);

  hipMemsetAsync(hist, 0, (size_t)N_NODES * 4, stream);

  const int eblocks = N_EDGES / 256;  // 3125, exact
  hist_cast<<<eblocks, 256, 0, stream>>>(dst, feat,
                                         f16_path ? feat16 : nullptr, hist,
                                         slot);
  scan_block<<<SCAN_BLOCKS, 256, 0, stream>>>(hist, row_start, bsum, W, WT16g);
  scan_add<<<SCAN_BLOCKS, 256, 0, stream>>>(bsum, row_start);
  scatter_kernel<<<(N_EDGES / 2 + 255) / 256, 256, 0, stream>>>(
      src, dst, row_start, slot, esrc);
  if (f16_path) {
    aggregate_f16<<<(N_NODES + 3) / 4, 256, 0, stream>>>(feat, feat16, esrc,
                                                         row_start,
                                                         (__half2*)x);
  } else {
    aggregate_f32<<<(N_NODES + 3) / 4, 256, 0, stream>>>(feat, esrc, row_start,
                                                         (__half2*)x);
  }
  mfma_gemm<<<(N_NODES + 255) / 256, 512, 0, stream>>>(
      (const _Float16*)x, WT16g, out);
}

// Round 8
// 201.058 us; speedup vs baseline: 1.0963x; 1.0963x over previous
//
#include <hip/hip_runtime.h>
#include <hip/hip_fp16.h>

#define N_NODES 50000
#define N_EDGES 800000
#define IN_DIM  128
#define OUT_DIM 256
#define SCAN_BLOCKS ((N_NODES + 255) / 256)  // 196
#define WT_STRIDE 136  // f16 elems; 272B rows -> 2-way-max bank spread (free)

typedef _Float16 f16x8 __attribute__((ext_vector_type(8)));
typedef float f32x4 __attribute__((ext_vector_type(4)));

// ---------------------------------------------------------------------------
// Uniform int64-vs-int32 detection (values < 2^31 -> int64 odd words all 0).
// ---------------------------------------------------------------------------
__device__ __forceinline__ int detect_i64(const int* __restrict__ idx) {
  int orv = 0;
#pragma unroll
  for (int j = 1; j < 32; j += 2) orv |= idx[j];
  return orv == 0;
}

// ---------------------------------------------------------------------------
// Kernel 1: dst histogram + per-edge slot + f32->f16 feat cast (fused).
// Grid 3125x256 covers N_EDGES exactly; cast covers 6.4M floats exactly.
// ---------------------------------------------------------------------------
__global__ __launch_bounds__(256) void hist_cast(
    const int* __restrict__ dst, const float* __restrict__ feat,
    __half* __restrict__ feat16, int* __restrict__ hist,
    int* __restrict__ slot) {
  const int f = detect_i64(dst);
  const int e = blockIdx.x * 256 + threadIdx.x;
  const int d = dst[f ? 2 * (long)e : (long)e];
  slot[e] = atomicAdd(&hist[d], 1);

  if (feat16 != nullptr) {
    size_t i = (size_t)e * 8;
    float4 v0 = *reinterpret_cast<const float4*>(feat + i);
    float4 v1 = *reinterpret_cast<const float4*>(feat + i + 4);
    __half2 h[4];
    h[0] = __floats2half2_rn(v0.x, v0.y);
    h[1] = __floats2half2_rn(v0.z, v0.w);
    h[2] = __floats2half2_rn(v1.x, v1.y);
    h[3] = __floats2half2_rn(v1.z, v1.w);
    *reinterpret_cast<float4*>(feat16 + i) = *reinterpret_cast<float4*>(h);
  }
}

// ---------------------------------------------------------------------------
// Kernel 2: per-block exclusive scan of hist into row_start + bsum.
// Blocks 0..127 additionally transpose+cast W into global WT16g[n][k].
// ---------------------------------------------------------------------------
__global__ __launch_bounds__(256) void scan_block(
    const int* __restrict__ hist, int* __restrict__ row_start,
    int* __restrict__ bsum, const float* __restrict__ W,
    __half* __restrict__ WT16g) {
  __shared__ int s[256];
  int tid = threadIdx.x;
  int i = blockIdx.x * 256 + tid;
  int v = (i < N_NODES) ? hist[i] : 0;
  s[tid] = v;
  __syncthreads();
  for (int off = 1; off < 256; off <<= 1) {
    int t = (tid >= off) ? s[tid - off] : 0;
    __syncthreads();
    s[tid] += t;
    __syncthreads();
  }
  if (i < N_NODES) row_start[i] = s[tid] - v;
  if (tid == 255) bsum[blockIdx.x] = s[255];

  if (blockIdx.x < 128) {  // W transpose: block b -> n rows 2b, 2b+1
    int n = 2 * blockIdx.x + (tid >> 7);
    int k = tid & 127;
    WT16g[n * IN_DIM + k] = __float2half(W[k * OUT_DIM + n]);
  }
}

// ---------------------------------------------------------------------------
// Kernel 3: add block prefix (redundant per-block reduce of bsum).
// ---------------------------------------------------------------------------
__global__ __launch_bounds__(256) void scan_add(
    const int* __restrict__ bsum, int* __restrict__ row_start) {
  __shared__ int sb[256];
  int tid = threadIdx.x;
  sb[tid] = (tid < (int)blockIdx.x) ? bsum[tid] : 0;
  __syncthreads();
  for (int off = 128; off > 0; off >>= 1) {
    if (tid < off) sb[tid] += sb[tid + off];
    __syncthreads();
  }
  int i = blockIdx.x * 256 + tid;
  if (i < N_NODES) row_start[i] += sb[0];
  if (i == 0) row_start[N_NODES] = N_EDGES;
}

// ---------------------------------------------------------------------------
// Kernel 4: scatter src into dst-sorted esrc, 2 edges/thread, vector loads.
// ---------------------------------------------------------------------------
__global__ __launch_bounds__(256) void scatter_kernel(
    const int* __restrict__ src, const int* __restrict__ dst,
    const int* __restrict__ row_start, const int* __restrict__ slot,
    int* __restrict__ esrc) {
  const int f = detect_i64(src);
  const int t = blockIdx.x * 256 + threadIdx.x;
  if (t >= N_EDGES / 2) return;
  int s0, s1, d0, d1;
  if (f) {
    int4 sv = *reinterpret_cast<const int4*>(src + 4 * (long)t);
    int4 dv = *reinterpret_cast<const int4*>(dst + 4 * (long)t);
    s0 = sv.x; s1 = sv.z; d0 = dv.x; d1 = dv.z;
  } else {
    int2 sv = *reinterpret_cast<const int2*>(src + 2 * (long)t);
    int2 dv = *reinterpret_cast<const int2*>(dst + 2 * (long)t);
    s0 = sv.x; s1 = sv.y; d0 = dv.x; d1 = dv.y;
  }
  int2 sl = *reinterpret_cast<const int2*>(slot + 2 * (long)t);
  esrc[row_start[d0] + sl.x] = s0;
  esrc[row_start[d1] + sl.y] = s1;
}

// ---------------------------------------------------------------------------
// Kernel 5: pull aggregation, one wave per node, unroll-4, CLEAN scalar tail
// (round-6 proven body: no duplicate gathers — the round-7 masked unroll-8
// wasted ~25% of gather bandwidth on clamped duplicate loads).
// ---------------------------------------------------------------------------
__global__ __launch_bounds__(256) void aggregate_f16(
    const float* __restrict__ feat, const __half* __restrict__ feat16,
    const int* __restrict__ esrc, const int* __restrict__ row_start,
    __half2* __restrict__ x) {
  int node = blockIdx.x * 4 + ((int)threadIdx.x >> 6);
  int lane = (int)threadIdx.x & 63;
  if (node >= N_NODES) return;
  int rs = row_start[node];
  int re = row_start[node + 1];
  float2 a0 = {0.f, 0.f}, a1 = {0.f, 0.f}, a2 = {0.f, 0.f}, a3 = {0.f, 0.f};
  int e = rs;
  for (; e + 3 < re; e += 4) {
    int s0 = esrc[e + 0];
    int s1 = esrc[e + 1];
    int s2 = esrc[e + 2];
    int s3 = esrc[e + 3];
    float2 v0 = __half22float2(*reinterpret_cast<const __half2*>(
        feat16 + (size_t)s0 * IN_DIM + lane * 2));
    float2 v1 = __half22float2(*reinterpret_cast<const __half2*>(
        feat16 + (size_t)s1 * IN_DIM + lane * 2));
    float2 v2 = __half22float2(*reinterpret_cast<const __half2*>(
        feat16 + (size_t)s2 * IN_DIM + lane * 2));
    float2 v3 = __half22float2(*reinterpret_cast<const __half2*>(
        feat16 + (size_t)s3 * IN_DIM + lane * 2));
    a0.x += v0.x; a0.y += v0.y;
    a1.x += v1.x; a1.y += v1.y;
    a2.x += v2.x; a2.y += v2.y;
    a3.x += v3.x; a3.y += v3.y;
  }
  for (; e < re; ++e) {
    float2 v0 = __half22float2(*reinterpret_cast<const __half2*>(
        feat16 + (size_t)esrc[e] * IN_DIM + lane * 2));
    a0.x += v0.x; a0.y += v0.y;
  }
  float deg = (float)(re - rs);
  float rdeg = (deg > 0.f) ? 1.0f / deg : 0.0f;
  float2 f = *reinterpret_cast<const float2*>(
      feat + (size_t)node * IN_DIM + lane * 2);
  float x0 = (f.x + ((a0.x + a1.x) + (a2.x + a3.x)) * rdeg) * 0.5f;
  float x1 = (f.y + ((a0.y + a1.y) + (a2.y + a3.y)) * rdeg) * 0.5f;
  x[(size_t)node * (IN_DIM / 2) + lane] = __floats2half2_rn(x0, x1);
}

// f32-gather fallback (only if workspace can't hold feat16).
__global__ __launch_bounds__(256) void aggregate_f32(
    const float* __restrict__ feat, const int* __restrict__ esrc,
    const int* __restrict__ row_start, __half2* __restrict__ x) {
  int node = blockIdx.x * 4 + ((int)threadIdx.x >> 6);
  int lane = (int)threadIdx.x & 63;
  if (node >= N_NODES) return;
  int rs = row_start[node];
  int re = row_start[node + 1];
  float2 a0 = {0.f, 0.f}, a1 = {0.f, 0.f};
  int e = rs;
  for (; e + 1 < re; e += 2) {
    float2 v0 = *reinterpret_cast<const float2*>(
        feat + (size_t)esrc[e] * IN_DIM + lane * 2);
    float2 v1 = *reinterpret_cast<const float2*>(
        feat + (size_t)esrc[e + 1] * IN_DIM + lane * 2);
    a0.x += v0.x; a0.y += v0.y;
    a1.x += v1.x; a1.y += v1.y;
  }
  if (e < re) {
    float2 v0 = *reinterpret_cast<const float2*>(
        feat + (size_t)esrc[e] * IN_DIM + lane * 2);
    a0.x += v0.x; a0.y += v0.y;
  }
  float deg = (float)(re - rs);
  float rdeg = (deg > 0.f) ? 1.0f / deg : 0.0f;
  float2 f = *reinterpret_cast<const float2*>(
      feat + (size_t)node * IN_DIM + lane * 2);
  float x0 = (f.x + (a0.x + a1.x) * rdeg) * 0.5f;
  float x1 = (f.y + (a0.y + a1.y) * rdeg) * 0.5f;
  x[(size_t)node * (IN_DIM / 2) + lane] = __floats2half2_rn(x0, x1);
}

// ---------------------------------------------------------------------------
// Kernel 6: MFMA GEMM out = relu(x @ W). 256 threads / 4 waves / 128 rows
// (391 blocks -> full CU coverage, 2 blocks/CU with 68 KiB LDS).
// WT staged from pre-transposed global WT16g via pure b128 copy.
// C/D layout (m89-verified): col=lane&15, row=(lane>>4)*4+reg.
// ---------------------------------------------------------------------------
__global__ __launch_bounds__(256) void mfma_gemm(
    const _Float16* __restrict__ x, const __half* __restrict__ WT16g,
    float* __restrict__ out) {
  __shared__ _Float16 WT[OUT_DIM * WT_STRIDE];  // 68 KiB -> 2 blocks/CU

  const int tid = threadIdx.x;
  // Stage: 64 KB = 4096 16B-chunks; thread t copies chunks t, t+256, ... (x16).
#pragma unroll
  for (int i = 0; i < 16; ++i) {
    int c = i * 256 + tid;          // 16B-chunk index
    int n = c >> 4;                 // 16 chunks per n-row (128 f16)
    int kc = c & 15;
    *reinterpret_cast<float4*>(&WT[n * WT_STRIDE + kc * 8]) =
        *reinterpret_cast<const float4*>(WT16g + c * 8);
  }
  __syncthreads();

  const int wave = tid >> 6;
  const int lane = tid & 63;
  const int m = lane & 15;
  const int g = lane >> 4;
  const long row_base = (long)blockIdx.x * 128 + wave * 32;

  f16x8 a[2][4];
#pragma unroll
  for (int rt = 0; rt < 2; ++rt) {
    long row = row_base + rt * 16 + m;
#pragma unroll
    for (int kt = 0; kt < 4; ++kt) {
      if (row < N_NODES) {
        a[rt][kt] = *reinterpret_cast<const f16x8*>(
            x + row * IN_DIM + kt * 32 + g * 8);
      } else {
        a[rt][kt] = f16x8{};
      }
    }
  }

#pragma unroll
  for (int nt = 0; nt < 16; ++nt) {
    f16x8 b[4];
#pragma unroll
    for (int kt = 0; kt < 4; ++kt) {
      b[kt] = *reinterpret_cast<const f16x8*>(
          &WT[(nt * 16 + m) * WT_STRIDE + kt * 32 + g * 8]);
    }
    f32x4 acc0 = {0.f, 0.f, 0.f, 0.f};
    f32x4 acc1 = {0.f, 0.f, 0.f, 0.f};
#pragma unroll
    for (int kt = 0; kt < 4; ++kt) {
      acc0 = __builtin_amdgcn_mfma_f32_16x16x32_f16(a[0][kt], b[kt], acc0, 0, 0, 0);
      acc1 = __builtin_amdgcn_mfma_f32_16x16x32_f16(a[1][kt], b[kt], acc1, 0, 0, 0);
    }
    const int col = nt * 16 + m;
#pragma unroll
    for (int j = 0; j < 4; ++j) {
      long r0 = row_base + g * 4 + j;
      long r1 = row_base + 16 + g * 4 + j;
      if (r0 < N_NODES)
        __builtin_nontemporal_store(fmaxf(acc0[j], 0.f),
                                    &out[r0 * OUT_DIM + col]);
      if (r1 < N_NODES)
        __builtin_nontemporal_store(fmaxf(acc1[j], 0.f),
                                    &out[r1 * OUT_DIM + col]);
    }
  }
}

extern "C" void kernel_launch(void* const* d_in, const int* in_sizes, int n_in,
                              void* d_out, int out_size, void* d_ws,
                              size_t ws_size, hipStream_t stream) {
  const float* feat = (const float*)d_in[0];
  const float* W = (const float*)d_in[1];
  const int* src = (const int*)d_in[2];
  const int* dst = (const int*)d_in[3];
  float* out = (float*)d_out;

  // Workspace (~29.3 MB; proven available by round-5/6/7 f16-path runs).
  // slot aliases x: slot dies (scatter) before x is born (aggregate).
  char* p = (char*)d_ws;
  __half* x = (__half*)p;    p += (size_t)N_NODES * IN_DIM * 2;  // 12.8 MB
  int* slot = (int*)x;                                           // 3.2 MB alias
  int* esrc = (int*)p;       p += (size_t)N_EDGES * 4;           // 3.2 MB
  int* hist = (int*)p;       p += (size_t)N_NODES * 4;           // 200 KB
  int* row_start = (int*)p;  p += (size_t)(N_NODES + 1) * 4;
  int* bsum = (int*)p;       p += 256 * 4;
  p = (char*)(((uintptr_t)p + 15) & ~(uintptr_t)15);
  __half* WT16g = (__half*)p; p += (size_t)OUT_DIM * IN_DIM * 2;  // 64 KB
  __half* feat16 = (__half*)p;
  size_t need_f16 =
      ((char*)feat16 - (char*)d_ws) + (size_t)N_NODES * IN_DIM * 2;
  const bool f16_path = (ws_size >= need_f16);

  hipMemsetAsync(hist, 0, (size_t)N_NODES * 4, stream);

  const int eblocks = N_EDGES / 256;  // 3125, exact
  hist_cast<<<eblocks, 256, 0, stream>>>(dst, feat,
                                         f16_path ? feat16 : nullptr, hist,
                                         slot);
  scan_block<<<SCAN_BLOCKS, 256, 0, stream>>>(hist, row_start, bsum, W, WT16g);
  scan_add<<<SCAN_BLOCKS, 256, 0, stream>>>(bsum, row_start);
  scatter_kernel<<<(N_EDGES / 2 + 255) / 256, 256, 0, stream>>>(
      src, dst, row_start, slot, esrc);
  if (f16_path) {
    aggregate_f16<<<(N_NODES + 3) / 4, 256, 0, stream>>>(feat, feat16, esrc,
                                                         row_start,
                                                         (__half2*)x);
  } else {
    aggregate_f32<<<(N_NODES + 3) / 4, 256, 0, stream>>>(feat, esrc, row_start,
                                                         (__half2*)x);
  }
  mfma_gemm<<<(N_NODES + 127) / 128, 256, 0, stream>>>(
      (const _Float16*)x, WT16g, out);
}